// Round 25
// baseline (215.701 us; speedup 1.0000x reference)
//
#include <hip/hip_runtime.h>

typedef unsigned short u16;
typedef __attribute__((ext_vector_type(8))) _Float16 half8;
typedef __attribute__((ext_vector_type(2))) __fp16 fp16x2;
typedef __attribute__((ext_vector_type(4))) float f32x4;
typedef __attribute__((ext_vector_type(16))) float f32x16;

#define MFMAH(A,B,C) __builtin_amdgcn_mfma_f32_16x16x32_f16(A,B,C,0,0,0)
#define MFMA32(A,B,C) __builtin_amdgcn_mfma_f32_32x32x16_f16(A,B,C,0,0,0)
#define LOG2E 1.4426950408889634f
#define C1 0.18033688011112042f   // 0.125 * log2(e)

__device__ __forceinline__ u16 f2h(float f){
  _Float16 h = (_Float16)f; u16 r; __builtin_memcpy(&r,&h,2); return r;
}
__device__ __forceinline__ float h2f(u16 v){
  _Float16 h; __builtin_memcpy(&h,&v,2); return (float)h;
}
__device__ __forceinline__ unsigned int pack_h2(float a, float b){
  fp16x2 h = __builtin_amdgcn_cvt_pkrtz(a,b);
  unsigned int r; __builtin_memcpy(&r,&h,4); return r;
}

// async global->LDS, 16B per lane; LDS dest = wave-uniform base + lane*16.
__device__ __forceinline__ void async_ld16(const void* g, void* l) {
  __builtin_amdgcn_global_load_lds(
      (const __attribute__((address_space(1))) unsigned int*)g,
      (__attribute__((address_space(3))) unsigned int*)l, 16, 0, 0);
}

// Cast hs (4M el) + Wq,Wk,Wv,Wo (1M each) fp32->f16 into contiguous ws.
__global__ __launch_bounds__(256) void cast_all(const float* __restrict__ hs,
    const float* __restrict__ wq, const float* __restrict__ wk,
    const float* __restrict__ wv, const float* __restrict__ wo,
    u16* __restrict__ dst)
{
  unsigned int i = blockIdx.x*256 + threadIdx.x;     // chunk of 8 elements
  size_t el = (size_t)i * 8;
  const float* src; size_t off;
  if (el < 4194304) { src = hs; off = el; }
  else {
    unsigned int r = (unsigned int)((el - 4194304) >> 20);
    src = (r==0)?wq:(r==1)?wk:(r==2)?wv:wo;
    off = (el - 4194304) & 1048575;
  }
  float4 a = *reinterpret_cast<const float4*>(src+off);
  float4 b = *reinterpret_cast<const float4*>(src+off+4);
  uint4 o = {pack_h2(a.x,a.y), pack_h2(a.z,a.w), pack_h2(b.x,b.y), pack_h2(b.z,b.w)};
  *reinterpret_cast<uint4*>(dst + el) = o;
}

// Fused QKV GEMM, 128x128 tiles, BK=32, 768 blocks (3/CU). W=[Wq;Wk;Wv].
// Best-measured BK=32 form (R11's BK=64+swizzle was null-to-negative:
// 2-phase critical path is stage+vmcnt+barrier).
// XCD-swizzled grid (T1): each XCD gets a 12n x 8m chunk so its W-panel (3MB)
// + A-panel (2MB) working set mostly fits the 4MB per-XCD L2.
// which = n0>>10: 0/1 -> q/k (SWAPPED operands, d-contiguous packed stores into
// [bh][s][d]); 2 -> v (normal order, s-contiguous packed stores into V^T [bh][d][s]).
__global__ __launch_bounds__(256) void gemm_qkv(const u16* __restrict__ A,
                                                const u16* __restrict__ W,
                                                const float* __restrict__ bqp,
                                                const float* __restrict__ bkp,
                                                const float* __restrict__ bvp,
                                                u16* __restrict__ qout,
                                                u16* __restrict__ kout,
                                                u16* __restrict__ vout,
                                                int M, int K)
{
  __shared__ __align__(16) u16 lds_a[128*32];
  __shared__ __align__(16) u16 lds_w[128*32];
  const int t = threadIdx.x;
  const int lane = t & 63, wave = t >> 6;
  const int wm = wave >> 1, wn = wave & 1;
  const int lr = lane & 15, quad = lane >> 4;
  // XCD-bijective decode: flat 0..767, xcd = flat&7 (HW round-robin),
  // per-XCD chunk = 12 n-blocks x 8 m-blocks.
  const int flat = blockIdx.x;
  const int xcd = flat & 7, slot = flat >> 3;     // slot 0..95
  const int ln = slot % 12, lm = slot / 12;       // 0..11, 0..7
  const int n0 = ((xcd & 1) * 12 + ln) * 128;
  const int m0 = ((xcd >> 1) * 8 + lm) * 128;
  const int wbase = t & 192;
  const int which = n0 >> 10;

  const f32x4 fzero = {0.f,0.f,0.f,0.f};
  f32x4 acc[4][4];
  #pragma unroll
  for (int i=0;i<4;++i)
    #pragma unroll
    for (int j=0;j<4;++j) acc[i][j] = fzero;

  if (which < 2) {                 // ---- q/k: swapped operands, D[n][m] ----
    for (int k0 = 0; k0 < K; k0 += 32) {
      __syncthreads();
      #pragma unroll
      for (int it=0; it<2; ++it) {
        int idx = it*256 + t;
        int row = idx >> 2, c8 = (idx & 3) * 8;
        int lbase = (it*256 + wbase) * 8;
        async_ld16(&A[(size_t)(m0+row)*K + k0 + c8], &lds_a[lbase]);
        async_ld16(&W[(size_t)(n0+row)*K + k0 + c8], &lds_w[lbase]);
      }
      __syncthreads();
      half8 af[4], bfr[4];
      #pragma unroll
      for (int mt=0; mt<4; ++mt)
        af[mt] = *reinterpret_cast<const half8*>(&lds_a[(wm*64 + mt*16 + lr)*32 + quad*8]);
      #pragma unroll
      for (int nt=0; nt<4; ++nt)
        bfr[nt] = *reinterpret_cast<const half8*>(&lds_w[(wn*64 + nt*16 + lr)*32 + quad*8]);
      #pragma unroll
      for (int mt=0; mt<4; ++mt)
        #pragma unroll
        for (int nt=0; nt<4; ++nt)
          acc[mt][nt] = MFMAH(bfr[nt], af[mt], acc[mt][nt]);
    }
    const float* bp = which ? bkp : bqp;
    u16* dst = which ? kout : qout;
    #pragma unroll
    for (int nt=0; nt<4; ++nt) {
      int nn = (n0 & 1023) + wn*64 + nt*16 + quad*4;   // 4 consecutive n on regs
      float4 bv = *reinterpret_cast<const float4*>(&bp[nn]);
      int hh = nn >> 6, d4 = nn & 63;
      #pragma unroll
      for (int mt=0; mt<4; ++mt) {
        int m = m0 + wm*64 + mt*16 + lr;
        int b = m >> 11, s = m & 2047;
        uint2 o = {pack_h2(acc[mt][nt][0]+bv.x, acc[mt][nt][1]+bv.y),
                   pack_h2(acc[mt][nt][2]+bv.z, acc[mt][nt][3]+bv.w)};
        *reinterpret_cast<uint2*>(&dst[((size_t)(b*16 + hh)*2048 + s)*64 + d4]) = o;
      }
    }
  } else {                         // ---- v: normal order, D[m][n] -> V^T ----
    for (int k0 = 0; k0 < K; k0 += 32) {
      __syncthreads();
      #pragma unroll
      for (int it=0; it<2; ++it) {
        int idx = it*256 + t;
        int row = idx >> 2, c8 = (idx & 3) * 8;
        int lbase = (it*256 + wbase) * 8;
        async_ld16(&A[(size_t)(m0+row)*K + k0 + c8], &lds_a[lbase]);
        async_ld16(&W[(size_t)(n0+row)*K + k0 + c8], &lds_w[lbase]);
      }
      __syncthreads();
      half8 af[4], bfr[4];
      #pragma unroll
      for (int mt=0; mt<4; ++mt)
        af[mt] = *reinterpret_cast<const half8*>(&lds_a[(wm*64 + mt*16 + lr)*32 + quad*8]);
      #pragma unroll
      for (int nt=0; nt<4; ++nt)
        bfr[nt] = *reinterpret_cast<const half8*>(&lds_w[(wn*64 + nt*16 + lr)*32 + quad*8]);
      #pragma unroll
      for (int mt=0; mt<4; ++mt)
        #pragma unroll
        for (int nt=0; nt<4; ++nt)
          acc[mt][nt] = MFMAH(af[mt], bfr[nt], acc[mt][nt]);
    }
    #pragma unroll
    for (int nt=0; nt<4; ++nt) {
      int nn = (n0 & 1023) + wn*64 + nt*16 + lr;
      float bv = bvp[nn];
      int hh = nn >> 6, d = nn & 63;
      #pragma unroll
      for (int mt=0; mt<4; ++mt) {
        int m = m0 + wm*64 + mt*16 + quad*4;
        int b = m >> 11, s = m & 2047;
        uint2 o = {pack_h2(acc[mt][nt][0]+bv, acc[mt][nt][1]+bv),
                   pack_h2(acc[mt][nt][2]+bv, acc[mt][nt][3]+bv)};
        *reinterpret_cast<uint2*>(&vout[((size_t)(b*16 + hh)*64 + d)*2048 + s]) = o;
      }
    }
  }
}

// Out-proj GEMM, SWAPPED operands: lane holds 4 consecutive n -> float4 stores.
// XCD-swizzled grid (T1): each XCD gets 16n x 4m (W 2MB + A 1MB fits L2).
__global__ __launch_bounds__(256) void gemm_o(const u16* __restrict__ A,
                                              const u16* __restrict__ W,
                                              const float* __restrict__ bias,
                                              float* __restrict__ O,
                                              int M, int N, int K)
{
  __shared__ __align__(16) u16 lds_a[128*32];
  __shared__ __align__(16) u16 lds_w[64*32];
  const int t = threadIdx.x;
  const int lane = t & 63, wm = t >> 6;      // wave owns 32 M-rows
  const int lr = lane & 15, quad = lane >> 4;
  const int flat = blockIdx.x;
  const int xcd = flat & 7, slot = flat >> 3;     // slot 0..63
  const int n0 = (slot & 15) * 64;
  const int m0 = ((xcd << 2) + (slot >> 4)) * 128;
  const int wbase = t & 192;

  const f32x4 fzero = {0.f,0.f,0.f,0.f};
  f32x4 acc[2][4];
  #pragma unroll
  for (int i=0;i<2;++i)
    #pragma unroll
    for (int j=0;j<4;++j) acc[i][j] = fzero;

  for (int k0 = 0; k0 < K; k0 += 32) {
    __syncthreads();
    #pragma unroll
    for (int it=0; it<2; ++it) {
      int idx = it*256 + t;
      int row = idx >> 2, c8 = (idx & 3) * 8;
      int lbase = (it*256 + wbase) * 8;
      async_ld16(&A[(size_t)(m0+row)*K + k0 + c8], &lds_a[lbase]);
    }
    async_ld16(&W[(size_t)(n0 + (t>>2))*K + k0 + (t&3)*8], &lds_w[wbase*8]);
    __syncthreads();
    half8 af[2], bfr[4];
    #pragma unroll
    for (int mt=0; mt<2; ++mt)
      af[mt] = *reinterpret_cast<const half8*>(&lds_a[(wm*32 + mt*16 + lr)*32 + quad*8]);
    #pragma unroll
    for (int nt=0; nt<4; ++nt)
      bfr[nt] = *reinterpret_cast<const half8*>(&lds_w[(nt*16 + lr)*32 + quad*8]);
    #pragma unroll
    for (int mt=0; mt<2; ++mt)
      #pragma unroll
      for (int nt=0; nt<4; ++nt)
        acc[mt][nt] = MFMAH(bfr[nt], af[mt], acc[mt][nt]);   // D[n][m]
  }

  #pragma unroll
  for (int nt=0; nt<4; ++nt) {
    int nb = n0 + nt*16 + quad*4;
    float4 bv = *reinterpret_cast<const float4*>(&bias[nb]);
    #pragma unroll
    for (int mt=0; mt<2; ++mt) {
      int m = m0 + wm*32 + mt*16 + lr;
      float4 o = {acc[mt][nt][0]+bv.x, acc[mt][nt][1]+bv.y,
                  acc[mt][nt][2]+bv.z, acc[mt][nt][3]+bv.w};
      *reinterpret_cast<float4*>(&O[(size_t)m * N + nb]) = o;
    }
  }
}

// In-place RMSNorm (over 1024 pre-split channels) + RoPE on [B,H,S,D] f16.
// One 256-thread block handles BOTH q and k for one (b,s): waves 0-1 = q,
// waves 2-3 = k. Reductions per-half via red[4].
__global__ __launch_bounds__(256) void rmsrope(u16* __restrict__ qb, u16* __restrict__ kb,
                                               const float* __restrict__ cosb,
                                               const float* __restrict__ sinb,
                                               const float* __restrict__ w)
{
  const int bs = blockIdx.x;
  const int b = bs >> 11, s = bs & 2047;
  const int t = threadIdx.x;                 // 256
  u16* buf = (t & 128) ? kb : qb;
  const int tl = t & 127;
  const int h = tl >> 3, d0 = (tl & 7) * 4;
  size_t base = ((size_t)(b*16+h)*2048 + s)*64;

  uint2 u1 = *reinterpret_cast<const uint2*>(&buf[base + d0]);
  uint2 u2 = *reinterpret_cast<const uint2*>(&buf[base + d0 + 32]);
  u16 a1[4], a2[4];
  __builtin_memcpy(a1, &u1, 8); __builtin_memcpy(a2, &u2, 8);
  float x1[4], x2[4];
  float ss = 0.f;
  #pragma unroll
  for (int j=0;j<4;++j){
    x1[j] = h2f(a1[j]); x2[j] = h2f(a2[j]);
    ss += x1[j]*x1[j] + x2[j]*x2[j];
  }
  #pragma unroll
  for (int off=32; off>0; off>>=1) ss += __shfl_xor(ss, off, 64);
  __shared__ float red[4];
  if ((t & 63) == 0) red[t>>6] = ss;
  __syncthreads();
  float tot = (t & 128) ? (red[2] + red[3]) : (red[0] + red[1]);
  float r = rsqrtf(tot * (1.0f/1024.0f) + 1e-6f);

  float4 w1 = *reinterpret_cast<const float4*>(&w[h*64+d0]);
  float4 w2 = *reinterpret_cast<const float4*>(&w[h*64+d0+32]);
  float4 c1 = *reinterpret_cast<const float4*>(&cosb[s*64+d0]);
  float4 s1 = *reinterpret_cast<const float4*>(&sinb[s*64+d0]);
  float4 c2 = *reinterpret_cast<const float4*>(&cosb[s*64+d0+32]);
  float4 s2 = *reinterpret_cast<const float4*>(&sinb[s*64+d0+32]);
  float n1[4] = {x1[0]*r*w1.x, x1[1]*r*w1.y, x1[2]*r*w1.z, x1[3]*r*w1.w};
  float n2[4] = {x2[0]*r*w2.x, x2[1]*r*w2.y, x2[2]*r*w2.z, x2[3]*r*w2.w};
  float o1[4] = {n1[0]*c1.x - n2[0]*s1.x, n1[1]*c1.y - n2[1]*s1.y,
                 n1[2]*c1.z - n2[2]*s1.z, n1[3]*c1.w - n2[3]*s1.w};
  float o2[4] = {n2[0]*c2.x + n1[0]*s2.x, n2[1]*c2.y + n1[1]*s2.y,
                 n2[2]*c2.z + n1[2]*s2.z, n2[3]*c2.w + n1[3]*s2.w};
  uint2 v1 = {pack_h2(o1[0],o1[1]), pack_h2(o1[2],o1[3])};
  uint2 v2 = {pack_h2(o2[0],o2[1]), pack_h2(o2[2],o2[3])};
  *reinterpret_cast<uint2*>(&buf[base + d0])      = v1;
  *reinterpret_cast<uint2*>(&buf[base + d0 + 32]) = v2;
}

// Flash attention, 32x32x16 MFMA. FINAL configuration (best measured:
// 210.5us total; attn 50.2-56.1us across 13 runs, VGPR 116, 0 conflicts).
// Structure: 64 q-rows/wave (qh=0,1 sub-tiles), BLOCK_Q=256, 8 waves =
// 4 q-waves x 2 key-groups (tiles 0-15/16-31), grid 256 = 1 block/CU.
// K/V fragments read from LDS ONCE, reused for both q-halves; QK and PV
// are 2 independent MFMA chains each. lsum on VALU (4 partials + shfl_xor).
// T14: prefetch issued after barrier, LDS-write after compute.
// S^T = K.Q^T (A=K,B=Q); O^T = V^T.P^T with vbuf in bit-swapped virtual-key
// order so S^T C-layout regs feed PV B-frags with no shuffles.
// pad-72 rows: 0 bank conflicts + coalesced staging. T1: XCD-bijective grid,
// 4 heads/XCD -> K/V 2MB fits per-XCD L2 (FETCH 69.7->12.3MB verified).
// __launch_bounds__(512,1): 2nd arg = blocks/CU on this toolchain.
// Mask is ADDITIVE (+1 allowed / +0 disallowed): all 32 tiles contribute.
// PLATEAU (13 runs, 210.5-216.8us): latency-bound at ~6% true MFMA occupancy;
// register file caps waves/SIMD. Tested-null/negative: T5/ones-MFMA (R8/R10),
// BK=64+T2 (R11), T15 pipeline (R14), LDS-diet (R3/R4). Further gains
// require the full co-designed 8-phase / 4-cluster rewrite (T2+T3+T4+T5).
__global__ __launch_bounds__(512, 1) void attn(const u16* __restrict__ qh,
                                               const u16* __restrict__ kh,
                                               const u16* __restrict__ vt,
                                               u16* __restrict__ ao)
{
  __shared__ __align__(16) u16 kbuf[2][2][64*72];   // [group][dbuf][key][d], pad 72
  __shared__ __align__(16) u16 vbuf[2][2][64*72];   // [group][dbuf][d][virtual-k]
  const int t = threadIdx.x;
  const int lane = t & 63, w = t >> 6;           // 8 waves
  const int g = w >> 2, wq = w & 3;              // key-group, q-wave
  const int ql = lane & 31, hf = lane >> 5;
  // XCD-bijective decode (flat 0..255, HW round-robins xcd = flat&7)
  const int flat = blockIdx.x;
  const int xcd = flat & 7, slot = flat >> 3;    // slot 0..31
  const int bh = xcd + ((slot >> 3) << 3);       // {xcd, xcd+8, xcd+16, xcd+24}
  const int qbase = (slot & 7) * 256;
  const int b = bh >> 4, h = bh & 15;
  const size_t hb = (size_t)bh * 2048 * 64;
  const u16* qp = qh + hb;
  const u16* kp = kh + hb;
  const u16* vtp = vt + hb;

  // Q fragments for both 32-q halves of this wave's 64 q rows.
  half8 qf[2][4];                                // [qh][s]: Q[d=s*16+hf*8+j][q]
  #pragma unroll
  for (int qh2=0; qh2<2; ++qh2) {
    int qa = qbase + wq*64 + qh2*32 + ql;
    #pragma unroll
    for (int s=0;s<4;++s)
      qf[qh2][s] = *reinterpret_cast<const half8*>(&qp[(size_t)qa*64 + s*16 + hf*8]);
  }

  // staging: 256 threads per group stage that group's tile.
  const int lt = t & 255;
  const int row = lt >> 3;                       // 0..31
  const int cc = lt & 7;
  const int base2 = 32*(cc>>2) + 16*((cc>>1)&1) + 4*(cc&1);  // keys base2+{0..3,8..11}
  const int kofs = row*72 + cc*8;
  const u16* kg = kp + (size_t)(g*1024 + row)*64 + cc*8;
  const u16* vg = vtp + (size_t)row*2048 + g*1024 + base2;

  const f32x16 fz16 = {0.f,0.f,0.f,0.f,0.f,0.f,0.f,0.f,0.f,0.f,0.f,0.f,0.f,0.f,0.f,0.f};
  f32x16 oacc[2][2];                             // [qh][dh]
  oacc[0][0]=fz16; oacc[0][1]=fz16; oacc[1][0]=fz16; oacc[1][1]=fz16;
  float lsum[2] = {0.f, 0.f};
  const int diag = (qbase + wq*64) >> 6;         // same tile for both qh halves

  // stage tile 0 of this group's range into buffer 0
  {
    uint4 k0v = *reinterpret_cast<const uint4*>(kg);
    uint4 k1v = *reinterpret_cast<const uint4*>(kg + 32*64);
    uint2 a0 = *reinterpret_cast<const uint2*>(vg);
    uint2 a1 = *reinterpret_cast<const uint2*>(vg + 8);
    uint2 b0 = *reinterpret_cast<const uint2*>(vg + (size_t)32*2048);
    uint2 b1 = *reinterpret_cast<const uint2*>(vg + (size_t)32*2048 + 8);
    *reinterpret_cast<uint4*>(&kbuf[g][0][kofs])        = k0v;
    *reinterpret_cast<uint4*>(&kbuf[g][0][kofs+32*72])  = k1v;
    uint4 v0 = {a0.x,a0.y,a1.x,a1.y};
    uint4 v1 = {b0.x,b0.y,b1.x,b1.y};
    *reinterpret_cast<uint4*>(&vbuf[g][0][kofs])        = v0;
    *reinterpret_cast<uint4*>(&vbuf[g][0][kofs+32*72])  = v1;
  }

  for (int kt=0; kt<16; ++kt) {
    __syncthreads();                             // buffers for kt ready
    // T14: issue next-tile loads after the barrier; compute covers latency.
    uint4 k0n, k1n; uint2 a0n, a1n, b0n, b1n;
    if (kt < 15) {
      const u16* kgn = kg + (size_t)(kt+1)*4096;
      const u16* vgn = vg + (kt+1)*64;
      k0n = *reinterpret_cast<const uint4*>(kgn);
      k1n = *reinterpret_cast<const uint4*>(kgn + 32*64);
      a0n = *reinterpret_cast<const uint2*>(vgn);
      a1n = *reinterpret_cast<const uint2*>(vgn + 8);
      b0n = *reinterpret_cast<const uint2*>(vgn + (size_t)32*2048);
      b1n = *reinterpret_cast<const uint2*>(vgn + (size_t)32*2048 + 8);
    }
    const u16* kb = &kbuf[g][kt & 1][0];
    const u16* vb = &vbuf[g][kt & 1][0];
    const int gkt = (g << 4) + kt;               // global key-tile index

    // S^T = K.Q^T (two 32-key halves x two q-halves); K-frags read ONCE.
    unsigned int pk[2][4][4];                    // [qh][st][word]
    #pragma unroll
    for (int kh2=0; kh2<2; ++kh2) {
      half8 kf[4];
      #pragma unroll
      for (int s=0;s<4;++s)
        __builtin_memcpy(&kf[s], &kb[(kh2*32+ql)*72 + s*16 + hf*8], 16);
      f32x16 z0 = fz16, z1 = fz16;               // independent chains (2x ILP)
      #pragma unroll
      for (int s=0;s<4;++s) z0 = MFMA32(kf[s], qf[0][s], z0);
      #pragma unroll
      for (int s=0;s<4;++s) z1 = MFMA32(kf[s], qf[1][s], z1);

      #pragma unroll
      for (int qh2=0; qh2<2; ++qh2) {
        const f32x16& z = qh2 ? z1 : z0;
        const int qa = qbase + wq*64 + qh2*32 + ql;
        float p[16];
        if (gkt != diag) {
          float ml = (gkt < diag) ? LOG2E : 0.0f;
          #pragma unroll
          for (int r=0;r<16;++r)
            p[r] = __builtin_amdgcn_exp2f(__builtin_fmaf(z[r], C1, ml));
        } else {
          #pragma unroll
          for (int r=0;r<16;++r) {
            int key = gkt*64 + kh2*32 + (r&3) + 8*(r>>2) + 4*hf;
            float ml = (key <= qa) ? LOG2E : 0.0f;
            p[r] = __builtin_amdgcn_exp2f(__builtin_fmaf(z[r], C1, ml));
          }
        }
        float ls0=0.f, ls1=0.f, ls2=0.f, ls3=0.f;  // 4-partial lsum (ILP)
        #pragma unroll
        for (int r=0;r<16;r+=4){ ls0+=p[r]; ls1+=p[r+1]; ls2+=p[r+2]; ls3+=p[r+3]; }
        lsum[qh2] += (ls0+ls1)+(ls2+ls3);
        #pragma unroll
        for (int t2=0;t2<2;++t2)
          #pragma unroll
          for (int jj=0;jj<4;++jj)
            pk[qh2][kh2*2+t2][jj] = pack_h2(p[t2*8+jj*2], p[t2*8+jj*2+1]);
      }
    }

    // O^T += V^T . P^T; V-frags read ONCE, reused for both q-halves.
    #pragma unroll
    for (int st=0;st<4;++st) {
      half8 vf0, vf1;
      __builtin_memcpy(&vf0, &vb[(0*32+ql)*72 + st*16 + hf*8], 16);
      __builtin_memcpy(&vf1, &vb[(1*32+ql)*72 + st*16 + hf*8], 16);
      #pragma unroll
      for (int qh2=0; qh2<2; ++qh2) {
        uint4 pq = {pk[qh2][st][0], pk[qh2][st][1], pk[qh2][st][2], pk[qh2][st][3]};
        half8 pf; __builtin_memcpy(&pf, &pq, 16);
        oacc[qh2][0] = MFMA32(vf0, pf, oacc[qh2][0]);
        oacc[qh2][1] = MFMA32(vf1, pf, oacc[qh2][1]);
      }
    }

    // write prefetched tile (vmcnt wait lands here, covered by compute)
    if (kt < 15) {
      u16* kwn = &kbuf[g][(kt+1)&1][kofs];
      u16* vwn = &vbuf[g][(kt+1)&1][kofs];
      *reinterpret_cast<uint4*>(kwn)         = k0n;
      *reinterpret_cast<uint4*>(kwn + 32*72) = k1n;
      uint4 v0 = {a0n.x,a0n.y,a1n.x,a1n.y};
      uint4 v1 = {b0n.x,b0n.y,b1n.x,b1n.y};
      *reinterpret_cast<uint4*>(vwn)         = v0;
      *reinterpret_cast<uint4*>(vwn + 32*72) = v1;
    }
  }

  // combine kh halves of lsum (lanes hf=0/1 hold disjoint key subsets)
  lsum[0] += __shfl_xor(lsum[0], 32, 64);
  lsum[1] += __shfl_xor(lsum[1], 32, 64);

  // ---- combine the two key-groups through LDS ----
  // qh=0 O-partials in kbuf (8 slices x 256 x 16B = 32KB), qh=1 in vbuf
  // (32KB); lsum in vbuf tail (+32KB, 2x256 floats).
  __syncthreads();                               // all compute on kbuf/vbuf done
  f32x4* xch0 = (f32x4*)&kbuf[0][0][0];
  f32x4* xch1 = (f32x4*)&vbuf[0][0][0];
  float* xls  = (float*)((char*)&vbuf[0][0][0] + 32768);
  const int idx = wq*64 + lane;
  if (g == 1) {
    #pragma unroll
    for (int qh2=0; qh2<2; ++qh2) {
      f32x4* xch = qh2 ? xch1 : xch0;
      #pragma unroll
      for (int dh=0; dh<2; ++dh)
        #pragma unroll
        for (int rq=0; rq<4; ++rq) {
          f32x4 v = {oacc[qh2][dh][rq*4+0], oacc[qh2][dh][rq*4+1],
                     oacc[qh2][dh][rq*4+2], oacc[qh2][dh][rq*4+3]};
          xch[(dh*4+rq)*256 + idx] = v;
        }
      xls[qh2*256 + idx] = lsum[qh2];
    }
  }
  __syncthreads();
  if (g == 0) {
    #pragma unroll
    for (int qh2=0; qh2<2; ++qh2) {
      f32x4* xch = qh2 ? xch1 : xch0;
      float inv = 1.0f / (lsum[qh2] + xls[qh2*256 + idx]);
      int qa = qbase + wq*64 + qh2*32 + ql;
      size_t rowbase = ((size_t)(b*2048 + qa))*1024 + h*64;
      #pragma unroll
      for (int dh=0; dh<2; ++dh)
        #pragma unroll
        for (int rq=0; rq<4; ++rq) {
          int dd = dh*32 + 8*rq + 4*hf;
          f32x4 v = xch[(dh*4+rq)*256 + idx];
          uint2 o = {pack_h2((oacc[qh2][dh][rq*4+0]+v.x)*inv, (oacc[qh2][dh][rq*4+1]+v.y)*inv),
                     pack_h2((oacc[qh2][dh][rq*4+2]+v.z)*inv, (oacc[qh2][dh][rq*4+3]+v.w)*inv)};
          *reinterpret_cast<uint2*>(&ao[rowbase + dd]) = o;
        }
    }
  }
}

extern "C" void kernel_launch(void* const* d_in, const int* in_sizes, int n_in,
                              void* d_out, int out_size, void* d_ws, size_t ws_size,
                              hipStream_t stream)
{
  const float* hs   = (const float*)d_in[0];
  const float* cosb = (const float*)d_in[1];
  const float* sinb = (const float*)d_in[2];
  const float* Wq   = (const float*)d_in[3];
  const float* bq   = (const float*)d_in[4];
  const float* Wk   = (const float*)d_in[5];
  const float* bk   = (const float*)d_in[6];
  const float* Wv   = (const float*)d_in[7];
  const float* bv   = (const float*)d_in[8];
  const float* Wo   = (const float*)d_in[9];
  const float* bo   = (const float*)d_in[10];
  const float* rw   = (const float*)d_in[11];

  const size_t NEL = (size_t)4096 * 1024;   // 4M
  const size_t WEL = (size_t)1024 * 1024;   // 1M
  u16* hsb = (u16*)d_ws;                    // f16 hs [4096,1024]
  u16* wqb = hsb + NEL;                     // Wq,Wk,Wv contiguous; then Wo
  u16* wob = wqb + 3*WEL;
  u16* qhb = wob + WEL;                     // q,k head layout; v -> V^T [bh][d][s]
  u16* khb = qhb + NEL;
  u16* vtb = khb + NEL;
  u16* aob = hsb;                           // reuse: hs consumed by QKV GEMM

  cast_all<<<4096, 256, 0, stream>>>(hs, Wq, Wk, Wv, Wo, hsb);
  gemm_qkv<<<768, 256, 0, stream>>>(hsb, wqb, bq, bk, bv, qhb, khb, vtb, 4096, 1024);
  rmsrope<<<4096, 256, 0, stream>>>(qhb, khb, cosb, sinb, rw);
  attn<<<256, 512, 0, stream>>>(qhb, khb, vtb, aob);
  gemm_o<<<512, 256, 0, stream>>>(aob, wob, bo, (float*)d_out, 4096, 1024, 1024);
}

// Round 26
// 214.021 us; speedup vs baseline: 1.0078x; 1.0078x over previous
//
#include <hip/hip_runtime.h>

typedef unsigned short u16;
typedef __attribute__((ext_vector_type(8))) _Float16 half8;
typedef __attribute__((ext_vector_type(2))) __fp16 fp16x2;
typedef __attribute__((ext_vector_type(4))) float f32x4;
typedef __attribute__((ext_vector_type(16))) float f32x16;

#define MFMAH(A,B,C) __builtin_amdgcn_mfma_f32_16x16x32_f16(A,B,C,0,0,0)
#define MFMA32(A,B,C) __builtin_amdgcn_mfma_f32_32x32x16_f16(A,B,C,0,0,0)
#define LOG2E 1.4426950408889634f
#define C1 0.18033688011112042f   // 0.125 * log2(e)

__device__ __forceinline__ u16 f2h(float f){
  _Float16 h = (_Float16)f; u16 r; __builtin_memcpy(&r,&h,2); return r;
}
__device__ __forceinline__ float h2f(u16 v){
  _Float16 h; __builtin_memcpy(&h,&v,2); return (float)h;
}
__device__ __forceinline__ unsigned int pack_h2(float a, float b){
  fp16x2 h = __builtin_amdgcn_cvt_pkrtz(a,b);
  unsigned int r; __builtin_memcpy(&r,&h,4); return r;
}

// async global->LDS, 16B per lane; LDS dest = wave-uniform base + lane*16.
__device__ __forceinline__ void async_ld16(const void* g, void* l) {
  __builtin_amdgcn_global_load_lds(
      (const __attribute__((address_space(1))) unsigned int*)g,
      (__attribute__((address_space(3))) unsigned int*)l, 16, 0, 0);
}

// Cast hs (4M el) + Wq,Wk,Wv,Wo (1M each) fp32->f16 into contiguous ws.
__global__ __launch_bounds__(256) void cast_all(const float* __restrict__ hs,
    const float* __restrict__ wq, const float* __restrict__ wk,
    const float* __restrict__ wv, const float* __restrict__ wo,
    u16* __restrict__ dst)
{
  unsigned int i = blockIdx.x*256 + threadIdx.x;     // chunk of 8 elements
  size_t el = (size_t)i * 8;
  const float* src; size_t off;
  if (el < 4194304) { src = hs; off = el; }
  else {
    unsigned int r = (unsigned int)((el - 4194304) >> 20);
    src = (r==0)?wq:(r==1)?wk:(r==2)?wv:wo;
    off = (el - 4194304) & 1048575;
  }
  float4 a = *reinterpret_cast<const float4*>(src+off);
  float4 b = *reinterpret_cast<const float4*>(src+off+4);
  uint4 o = {pack_h2(a.x,a.y), pack_h2(a.z,a.w), pack_h2(b.x,b.y), pack_h2(b.z,b.w)};
  *reinterpret_cast<uint4*>(dst + el) = o;
}

// Fused QKV GEMM, 128x128 tiles, BK=32, 768 blocks (3/CU). W=[Wq;Wk;Wv].
// Best-measured BK=32 form (R11's BK=64+swizzle was null-to-negative:
// 2-phase critical path is stage+vmcnt+barrier).
// XCD-swizzled grid (T1): each XCD gets a 12n x 8m chunk so its W-panel (3MB)
// + A-panel (2MB) working set mostly fits the 4MB per-XCD L2.
// which = n0>>10: 0/1 -> q/k (SWAPPED operands, d-contiguous packed stores into
// [bh][s][d]); 2 -> v (normal order, s-contiguous packed stores into V^T [bh][d][s]).
__global__ __launch_bounds__(256) void gemm_qkv(const u16* __restrict__ A,
                                                const u16* __restrict__ W,
                                                const float* __restrict__ bqp,
                                                const float* __restrict__ bkp,
                                                const float* __restrict__ bvp,
                                                u16* __restrict__ qout,
                                                u16* __restrict__ kout,
                                                u16* __restrict__ vout,
                                                int M, int K)
{
  __shared__ __align__(16) u16 lds_a[128*32];
  __shared__ __align__(16) u16 lds_w[128*32];
  const int t = threadIdx.x;
  const int lane = t & 63, wave = t >> 6;
  const int wm = wave >> 1, wn = wave & 1;
  const int lr = lane & 15, quad = lane >> 4;
  // XCD-bijective decode: flat 0..767, xcd = flat&7 (HW round-robin),
  // per-XCD chunk = 12 n-blocks x 8 m-blocks.
  const int flat = blockIdx.x;
  const int xcd = flat & 7, slot = flat >> 3;     // slot 0..95
  const int ln = slot % 12, lm = slot / 12;       // 0..11, 0..7
  const int n0 = ((xcd & 1) * 12 + ln) * 128;
  const int m0 = ((xcd >> 1) * 8 + lm) * 128;
  const int wbase = t & 192;
  const int which = n0 >> 10;

  const f32x4 fzero = {0.f,0.f,0.f,0.f};
  f32x4 acc[4][4];
  #pragma unroll
  for (int i=0;i<4;++i)
    #pragma unroll
    for (int j=0;j<4;++j) acc[i][j] = fzero;

  if (which < 2) {                 // ---- q/k: swapped operands, D[n][m] ----
    for (int k0 = 0; k0 < K; k0 += 32) {
      __syncthreads();
      #pragma unroll
      for (int it=0; it<2; ++it) {
        int idx = it*256 + t;
        int row = idx >> 2, c8 = (idx & 3) * 8;
        int lbase = (it*256 + wbase) * 8;
        async_ld16(&A[(size_t)(m0+row)*K + k0 + c8], &lds_a[lbase]);
        async_ld16(&W[(size_t)(n0+row)*K + k0 + c8], &lds_w[lbase]);
      }
      __syncthreads();
      half8 af[4], bfr[4];
      #pragma unroll
      for (int mt=0; mt<4; ++mt)
        af[mt] = *reinterpret_cast<const half8*>(&lds_a[(wm*64 + mt*16 + lr)*32 + quad*8]);
      #pragma unroll
      for (int nt=0; nt<4; ++nt)
        bfr[nt] = *reinterpret_cast<const half8*>(&lds_w[(wn*64 + nt*16 + lr)*32 + quad*8]);
      #pragma unroll
      for (int mt=0; mt<4; ++mt)
        #pragma unroll
        for (int nt=0; nt<4; ++nt)
          acc[mt][nt] = MFMAH(bfr[nt], af[mt], acc[mt][nt]);
    }
    const float* bp = which ? bkp : bqp;
    u16* dst = which ? kout : qout;
    #pragma unroll
    for (int nt=0; nt<4; ++nt) {
      int nn = (n0 & 1023) + wn*64 + nt*16 + quad*4;   // 4 consecutive n on regs
      float4 bv = *reinterpret_cast<const float4*>(&bp[nn]);
      int hh = nn >> 6, d4 = nn & 63;
      #pragma unroll
      for (int mt=0; mt<4; ++mt) {
        int m = m0 + wm*64 + mt*16 + lr;
        int b = m >> 11, s = m & 2047;
        uint2 o = {pack_h2(acc[mt][nt][0]+bv.x, acc[mt][nt][1]+bv.y),
                   pack_h2(acc[mt][nt][2]+bv.z, acc[mt][nt][3]+bv.w)};
        *reinterpret_cast<uint2*>(&dst[((size_t)(b*16 + hh)*2048 + s)*64 + d4]) = o;
      }
    }
  } else {                         // ---- v: normal order, D[m][n] -> V^T ----
    for (int k0 = 0; k0 < K; k0 += 32) {
      __syncthreads();
      #pragma unroll
      for (int it=0; it<2; ++it) {
        int idx = it*256 + t;
        int row = idx >> 2, c8 = (idx & 3) * 8;
        int lbase = (it*256 + wbase) * 8;
        async_ld16(&A[(size_t)(m0+row)*K + k0 + c8], &lds_a[lbase]);
        async_ld16(&W[(size_t)(n0+row)*K + k0 + c8], &lds_w[lbase]);
      }
      __syncthreads();
      half8 af[4], bfr[4];
      #pragma unroll
      for (int mt=0; mt<4; ++mt)
        af[mt] = *reinterpret_cast<const half8*>(&lds_a[(wm*64 + mt*16 + lr)*32 + quad*8]);
      #pragma unroll
      for (int nt=0; nt<4; ++nt)
        bfr[nt] = *reinterpret_cast<const half8*>(&lds_w[(wn*64 + nt*16 + lr)*32 + quad*8]);
      #pragma unroll
      for (int mt=0; mt<4; ++mt)
        #pragma unroll
        for (int nt=0; nt<4; ++nt)
          acc[mt][nt] = MFMAH(af[mt], bfr[nt], acc[mt][nt]);
    }
    #pragma unroll
    for (int nt=0; nt<4; ++nt) {
      int nn = (n0 & 1023) + wn*64 + nt*16 + lr;
      float bv = bvp[nn];
      int hh = nn >> 6, d = nn & 63;
      #pragma unroll
      for (int mt=0; mt<4; ++mt) {
        int m = m0 + wm*64 + mt*16 + quad*4;
        int b = m >> 11, s = m & 2047;
        uint2 o = {pack_h2(acc[mt][nt][0]+bv, acc[mt][nt][1]+bv),
                   pack_h2(acc[mt][nt][2]+bv, acc[mt][nt][3]+bv)};
        *reinterpret_cast<uint2*>(&vout[((size_t)(b*16 + hh)*64 + d)*2048 + s]) = o;
      }
    }
  }
}

// Out-proj GEMM, SWAPPED operands: lane holds 4 consecutive n -> float4 stores.
// XCD-swizzled grid (T1): each XCD gets 16n x 4m (W 2MB + A 1MB fits L2).
__global__ __launch_bounds__(256) void gemm_o(const u16* __restrict__ A,
                                              const u16* __restrict__ W,
                                              const float* __restrict__ bias,
                                              float* __restrict__ O,
                                              int M, int N, int K)
{
  __shared__ __align__(16) u16 lds_a[128*32];
  __shared__ __align__(16) u16 lds_w[64*32];
  const int t = threadIdx.x;
  const int lane = t & 63, wm = t >> 6;      // wave owns 32 M-rows
  const int lr = lane & 15, quad = lane >> 4;
  const int flat = blockIdx.x;
  const int xcd = flat & 7, slot = flat >> 3;     // slot 0..63
  const int n0 = (slot & 15) * 64;
  const int m0 = ((xcd << 2) + (slot >> 4)) * 128;
  const int wbase = t & 192;

  const f32x4 fzero = {0.f,0.f,0.f,0.f};
  f32x4 acc[2][4];
  #pragma unroll
  for (int i=0;i<2;++i)
    #pragma unroll
    for (int j=0;j<4;++j) acc[i][j] = fzero;

  for (int k0 = 0; k0 < K; k0 += 32) {
    __syncthreads();
    #pragma unroll
    for (int it=0; it<2; ++it) {
      int idx = it*256 + t;
      int row = idx >> 2, c8 = (idx & 3) * 8;
      int lbase = (it*256 + wbase) * 8;
      async_ld16(&A[(size_t)(m0+row)*K + k0 + c8], &lds_a[lbase]);
    }
    async_ld16(&W[(size_t)(n0 + (t>>2))*K + k0 + (t&3)*8], &lds_w[wbase*8]);
    __syncthreads();
    half8 af[2], bfr[4];
    #pragma unroll
    for (int mt=0; mt<2; ++mt)
      af[mt] = *reinterpret_cast<const half8*>(&lds_a[(wm*32 + mt*16 + lr)*32 + quad*8]);
    #pragma unroll
    for (int nt=0; nt<4; ++nt)
      bfr[nt] = *reinterpret_cast<const half8*>(&lds_w[(nt*16 + lr)*32 + quad*8]);
    #pragma unroll
    for (int mt=0; mt<2; ++mt)
      #pragma unroll
      for (int nt=0; nt<4; ++nt)
        acc[mt][nt] = MFMAH(bfr[nt], af[mt], acc[mt][nt]);   // D[n][m]
  }

  #pragma unroll
  for (int nt=0; nt<4; ++nt) {
    int nb = n0 + nt*16 + quad*4;
    float4 bv = *reinterpret_cast<const float4*>(&bias[nb]);
    #pragma unroll
    for (int mt=0; mt<2; ++mt) {
      int m = m0 + wm*32 + mt*16 + lr;
      float4 o = {acc[mt][nt][0]+bv.x, acc[mt][nt][1]+bv.y,
                  acc[mt][nt][2]+bv.z, acc[mt][nt][3]+bv.w};
      *reinterpret_cast<float4*>(&O[(size_t)m * N + nb]) = o;
    }
  }
}

// In-place RMSNorm (over 1024 pre-split channels) + RoPE on [B,H,S,D] f16.
// One 256-thread block handles BOTH q and k for one (b,s): waves 0-1 = q,
// waves 2-3 = k. Reductions per-half via red[4].
__global__ __launch_bounds__(256) void rmsrope(u16* __restrict__ qb, u16* __restrict__ kb,
                                               const float* __restrict__ cosb,
                                               const float* __restrict__ sinb,
                                               const float* __restrict__ w)
{
  const int bs = blockIdx.x;
  const int b = bs >> 11, s = bs & 2047;
  const int t = threadIdx.x;                 // 256
  u16* buf = (t & 128) ? kb : qb;
  const int tl = t & 127;
  const int h = tl >> 3, d0 = (tl & 7) * 4;
  size_t base = ((size_t)(b*16+h)*2048 + s)*64;

  uint2 u1 = *reinterpret_cast<const uint2*>(&buf[base + d0]);
  uint2 u2 = *reinterpret_cast<const uint2*>(&buf[base + d0 + 32]);
  u16 a1[4], a2[4];
  __builtin_memcpy(a1, &u1, 8); __builtin_memcpy(a2, &u2, 8);
  float x1[4], x2[4];
  float ss = 0.f;
  #pragma unroll
  for (int j=0;j<4;++j){
    x1[j] = h2f(a1[j]); x2[j] = h2f(a2[j]);
    ss += x1[j]*x1[j] + x2[j]*x2[j];
  }
  #pragma unroll
  for (int off=32; off>0; off>>=1) ss += __shfl_xor(ss, off, 64);
  __shared__ float red[4];
  if ((t & 63) == 0) red[t>>6] = ss;
  __syncthreads();
  float tot = (t & 128) ? (red[2] + red[3]) : (red[0] + red[1]);
  float r = rsqrtf(tot * (1.0f/1024.0f) + 1e-6f);

  float4 w1 = *reinterpret_cast<const float4*>(&w[h*64+d0]);
  float4 w2 = *reinterpret_cast<const float4*>(&w[h*64+d0+32]);
  float4 c1 = *reinterpret_cast<const float4*>(&cosb[s*64+d0]);
  float4 s1 = *reinterpret_cast<const float4*>(&sinb[s*64+d0]);
  float4 c2 = *reinterpret_cast<const float4*>(&cosb[s*64+d0+32]);
  float4 s2 = *reinterpret_cast<const float4*>(&sinb[s*64+d0+32]);
  float n1[4] = {x1[0]*r*w1.x, x1[1]*r*w1.y, x1[2]*r*w1.z, x1[3]*r*w1.w};
  float n2[4] = {x2[0]*r*w2.x, x2[1]*r*w2.y, x2[2]*r*w2.z, x2[3]*r*w2.w};
  float o1[4] = {n1[0]*c1.x - n2[0]*s1.x, n1[1]*c1.y - n2[1]*s1.y,
                 n1[2]*c1.z - n2[2]*s1.z, n1[3]*c1.w - n2[3]*s1.w};
  float o2[4] = {n2[0]*c2.x + n1[0]*s2.x, n2[1]*c2.y + n1[1]*s2.y,
                 n2[2]*c2.z + n1[2]*s2.z, n2[3]*c2.w + n1[3]*s2.w};
  uint2 v1 = {pack_h2(o1[0],o1[1]), pack_h2(o1[2],o1[3])};
  uint2 v2 = {pack_h2(o2[0],o2[1]), pack_h2(o2[2],o2[3])};
  *reinterpret_cast<uint2*>(&buf[base + d0])      = v1;
  *reinterpret_cast<uint2*>(&buf[base + d0 + 32]) = v2;
}

// Flash attention, 32x32x16 MFMA. FINAL configuration (best measured:
// 210.5us total; attn 50.2-56.1us across 14 runs, VGPR 116, 0 conflicts).
// Structure: 64 q-rows/wave (qh=0,1 sub-tiles), BLOCK_Q=256, 8 waves =
// 4 q-waves x 2 key-groups (tiles 0-15/16-31), grid 256 = 1 block/CU.
// K/V fragments read from LDS ONCE, reused for both q-halves; QK and PV
// are 2 independent MFMA chains each. lsum on VALU (4 partials + shfl_xor).
// T14: prefetch issued after barrier, LDS-write after compute.
// S^T = K.Q^T (A=K,B=Q); O^T = V^T.P^T with vbuf in bit-swapped virtual-key
// order so S^T C-layout regs feed PV B-frags with no shuffles.
// pad-72 rows: 0 bank conflicts + coalesced staging. T1: XCD-bijective grid,
// 4 heads/XCD -> K/V 2MB fits per-XCD L2 (FETCH 69.7->12.3MB verified).
// __launch_bounds__(512,1): 2nd arg = blocks/CU on this toolchain.
// Mask is ADDITIVE (+1 allowed / +0 disallowed): all 32 tiles contribute.
// PLATEAU (14 runs, 210.5-216.8us): latency-bound at ~6% true MFMA occupancy;
// register file caps waves/SIMD. Tested-null/negative: T5/ones-MFMA (R8/R10),
// BK=64+T2 (R11), T15 pipeline (R14), LDS-diet (R3/R4). Further gains
// require the full co-designed 8-phase / 4-cluster rewrite (T2+T3+T4+T5).
__global__ __launch_bounds__(512, 1) void attn(const u16* __restrict__ qh,
                                               const u16* __restrict__ kh,
                                               const u16* __restrict__ vt,
                                               u16* __restrict__ ao)
{
  __shared__ __align__(16) u16 kbuf[2][2][64*72];   // [group][dbuf][key][d], pad 72
  __shared__ __align__(16) u16 vbuf[2][2][64*72];   // [group][dbuf][d][virtual-k]
  const int t = threadIdx.x;
  const int lane = t & 63, w = t >> 6;           // 8 waves
  const int g = w >> 2, wq = w & 3;              // key-group, q-wave
  const int ql = lane & 31, hf = lane >> 5;
  // XCD-bijective decode (flat 0..255, HW round-robins xcd = flat&7)
  const int flat = blockIdx.x;
  const int xcd = flat & 7, slot = flat >> 3;    // slot 0..31
  const int bh = xcd + ((slot >> 3) << 3);       // {xcd, xcd+8, xcd+16, xcd+24}
  const int qbase = (slot & 7) * 256;
  const int b = bh >> 4, h = bh & 15;
  const size_t hb = (size_t)bh * 2048 * 64;
  const u16* qp = qh + hb;
  const u16* kp = kh + hb;
  const u16* vtp = vt + hb;

  // Q fragments for both 32-q halves of this wave's 64 q rows.
  half8 qf[2][4];                                // [qh][s]: Q[d=s*16+hf*8+j][q]
  #pragma unroll
  for (int qh2=0; qh2<2; ++qh2) {
    int qa = qbase + wq*64 + qh2*32 + ql;
    #pragma unroll
    for (int s=0;s<4;++s)
      qf[qh2][s] = *reinterpret_cast<const half8*>(&qp[(size_t)qa*64 + s*16 + hf*8]);
  }

  // staging: 256 threads per group stage that group's tile.
  const int lt = t & 255;
  const int row = lt >> 3;                       // 0..31
  const int cc = lt & 7;
  const int base2 = 32*(cc>>2) + 16*((cc>>1)&1) + 4*(cc&1);  // keys base2+{0..3,8..11}
  const int kofs = row*72 + cc*8;
  const u16* kg = kp + (size_t)(g*1024 + row)*64 + cc*8;
  const u16* vg = vtp + (size_t)row*2048 + g*1024 + base2;

  const f32x16 fz16 = {0.f,0.f,0.f,0.f,0.f,0.f,0.f,0.f,0.f,0.f,0.f,0.f,0.f,0.f,0.f,0.f};
  f32x16 oacc[2][2];                             // [qh][dh]
  oacc[0][0]=fz16; oacc[0][1]=fz16; oacc[1][0]=fz16; oacc[1][1]=fz16;
  float lsum[2] = {0.f, 0.f};
  const int diag = (qbase + wq*64) >> 6;         // same tile for both qh halves

  // stage tile 0 of this group's range into buffer 0
  {
    uint4 k0v = *reinterpret_cast<const uint4*>(kg);
    uint4 k1v = *reinterpret_cast<const uint4*>(kg + 32*64);
    uint2 a0 = *reinterpret_cast<const uint2*>(vg);
    uint2 a1 = *reinterpret_cast<const uint2*>(vg + 8);
    uint2 b0 = *reinterpret_cast<const uint2*>(vg + (size_t)32*2048);
    uint2 b1 = *reinterpret_cast<const uint2*>(vg + (size_t)32*2048 + 8);
    *reinterpret_cast<uint4*>(&kbuf[g][0][kofs])        = k0v;
    *reinterpret_cast<uint4*>(&kbuf[g][0][kofs+32*72])  = k1v;
    uint4 v0 = {a0.x,a0.y,a1.x,a1.y};
    uint4 v1 = {b0.x,b0.y,b1.x,b1.y};
    *reinterpret_cast<uint4*>(&vbuf[g][0][kofs])        = v0;
    *reinterpret_cast<uint4*>(&vbuf[g][0][kofs+32*72])  = v1;
  }

  for (int kt=0; kt<16; ++kt) {
    __syncthreads();                             // buffers for kt ready
    // T14: issue next-tile loads after the barrier; compute covers latency.
    uint4 k0n, k1n; uint2 a0n, a1n, b0n, b1n;
    if (kt < 15) {
      const u16* kgn = kg + (size_t)(kt+1)*4096;
      const u16* vgn = vg + (kt+1)*64;
      k0n = *reinterpret_cast<const uint4*>(kgn);
      k1n = *reinterpret_cast<const uint4*>(kgn + 32*64);
      a0n = *reinterpret_cast<const uint2*>(vgn);
      a1n = *reinterpret_cast<const uint2*>(vgn + 8);
      b0n = *reinterpret_cast<const uint2*>(vgn + (size_t)32*2048);
      b1n = *reinterpret_cast<const uint2*>(vgn + (size_t)32*2048 + 8);
    }
    const u16* kb = &kbuf[g][kt & 1][0];
    const u16* vb = &vbuf[g][kt & 1][0];
    const int gkt = (g << 4) + kt;               // global key-tile index

    // S^T = K.Q^T (two 32-key halves x two q-halves); K-frags read ONCE.
    unsigned int pk[2][4][4];                    // [qh][st][word]
    #pragma unroll
    for (int kh2=0; kh2<2; ++kh2) {
      half8 kf[4];
      #pragma unroll
      for (int s=0;s<4;++s)
        __builtin_memcpy(&kf[s], &kb[(kh2*32+ql)*72 + s*16 + hf*8], 16);
      f32x16 z0 = fz16, z1 = fz16;               // independent chains (2x ILP)
      #pragma unroll
      for (int s=0;s<4;++s) z0 = MFMA32(kf[s], qf[0][s], z0);
      #pragma unroll
      for (int s=0;s<4;++s) z1 = MFMA32(kf[s], qf[1][s], z1);

      #pragma unroll
      for (int qh2=0; qh2<2; ++qh2) {
        const f32x16& z = qh2 ? z1 : z0;
        const int qa = qbase + wq*64 + qh2*32 + ql;
        float p[16];
        if (gkt != diag) {
          float ml = (gkt < diag) ? LOG2E : 0.0f;
          #pragma unroll
          for (int r=0;r<16;++r)
            p[r] = __builtin_amdgcn_exp2f(__builtin_fmaf(z[r], C1, ml));
        } else {
          #pragma unroll
          for (int r=0;r<16;++r) {
            int key = gkt*64 + kh2*32 + (r&3) + 8*(r>>2) + 4*hf;
            float ml = (key <= qa) ? LOG2E : 0.0f;
            p[r] = __builtin_amdgcn_exp2f(__builtin_fmaf(z[r], C1, ml));
          }
        }
        float ls0=0.f, ls1=0.f, ls2=0.f, ls3=0.f;  // 4-partial lsum (ILP)
        #pragma unroll
        for (int r=0;r<16;r+=4){ ls0+=p[r]; ls1+=p[r+1]; ls2+=p[r+2]; ls3+=p[r+3]; }
        lsum[qh2] += (ls0+ls1)+(ls2+ls3);
        #pragma unroll
        for (int t2=0;t2<2;++t2)
          #pragma unroll
          for (int jj=0;jj<4;++jj)
            pk[qh2][kh2*2+t2][jj] = pack_h2(p[t2*8+jj*2], p[t2*8+jj*2+1]);
      }
    }

    // O^T += V^T . P^T; V-frags read ONCE, reused for both q-halves.
    #pragma unroll
    for (int st=0;st<4;++st) {
      half8 vf0, vf1;
      __builtin_memcpy(&vf0, &vb[(0*32+ql)*72 + st*16 + hf*8], 16);
      __builtin_memcpy(&vf1, &vb[(1*32+ql)*72 + st*16 + hf*8], 16);
      #pragma unroll
      for (int qh2=0; qh2<2; ++qh2) {
        uint4 pq = {pk[qh2][st][0], pk[qh2][st][1], pk[qh2][st][2], pk[qh2][st][3]};
        half8 pf; __builtin_memcpy(&pf, &pq, 16);
        oacc[qh2][0] = MFMA32(vf0, pf, oacc[qh2][0]);
        oacc[qh2][1] = MFMA32(vf1, pf, oacc[qh2][1]);
      }
    }

    // write prefetched tile (vmcnt wait lands here, covered by compute)
    if (kt < 15) {
      u16* kwn = &kbuf[g][(kt+1)&1][kofs];
      u16* vwn = &vbuf[g][(kt+1)&1][kofs];
      *reinterpret_cast<uint4*>(kwn)         = k0n;
      *reinterpret_cast<uint4*>(kwn + 32*72) = k1n;
      uint4 v0 = {a0n.x,a0n.y,a1n.x,a1n.y};
      uint4 v1 = {b0n.x,b0n.y,b1n.x,b1n.y};
      *reinterpret_cast<uint4*>(vwn)         = v0;
      *reinterpret_cast<uint4*>(vwn + 32*72) = v1;
    }
  }

  // combine kh halves of lsum (lanes hf=0/1 hold disjoint key subsets)
  lsum[0] += __shfl_xor(lsum[0], 32, 64);
  lsum[1] += __shfl_xor(lsum[1], 32, 64);

  // ---- combine the two key-groups through LDS ----
  // qh=0 O-partials in kbuf (8 slices x 256 x 16B = 32KB), qh=1 in vbuf
  // (32KB); lsum in vbuf tail (+32KB, 2x256 floats).
  __syncthreads();                               // all compute on kbuf/vbuf done
  f32x4* xch0 = (f32x4*)&kbuf[0][0][0];
  f32x4* xch1 = (f32x4*)&vbuf[0][0][0];
  float* xls  = (float*)((char*)&vbuf[0][0][0] + 32768);
  const int idx = wq*64 + lane;
  if (g == 1) {
    #pragma unroll
    for (int qh2=0; qh2<2; ++qh2) {
      f32x4* xch = qh2 ? xch1 : xch0;
      #pragma unroll
      for (int dh=0; dh<2; ++dh)
        #pragma unroll
        for (int rq=0; rq<4; ++rq) {
          f32x4 v = {oacc[qh2][dh][rq*4+0], oacc[qh2][dh][rq*4+1],
                     oacc[qh2][dh][rq*4+2], oacc[qh2][dh][rq*4+3]};
          xch[(dh*4+rq)*256 + idx] = v;
        }
      xls[qh2*256 + idx] = lsum[qh2];
    }
  }
  __syncthreads();
  if (g == 0) {
    #pragma unroll
    for (int qh2=0; qh2<2; ++qh2) {
      f32x4* xch = qh2 ? xch1 : xch0;
      float inv = 1.0f / (lsum[qh2] + xls[qh2*256 + idx]);
      int qa = qbase + wq*64 + qh2*32 + ql;
      size_t rowbase = ((size_t)(b*2048 + qa))*1024 + h*64;
      #pragma unroll
      for (int dh=0; dh<2; ++dh)
        #pragma unroll
        for (int rq=0; rq<4; ++rq) {
          int dd = dh*32 + 8*rq + 4*hf;
          f32x4 v = xch[(dh*4+rq)*256 + idx];
          uint2 o = {pack_h2((oacc[qh2][dh][rq*4+0]+v.x)*inv, (oacc[qh2][dh][rq*4+1]+v.y)*inv),
                     pack_h2((oacc[qh2][dh][rq*4+2]+v.z)*inv, (oacc[qh2][dh][rq*4+3]+v.w)*inv)};
          *reinterpret_cast<uint2*>(&ao[rowbase + dd]) = o;
        }
    }
  }
}

extern "C" void kernel_launch(void* const* d_in, const int* in_sizes, int n_in,
                              void* d_out, int out_size, void* d_ws, size_t ws_size,
                              hipStream_t stream)
{
  const float* hs   = (const float*)d_in[0];
  const float* cosb = (const float*)d_in[1];
  const float* sinb = (const float*)d_in[2];
  const float* Wq   = (const float*)d_in[3];
  const float* bq   = (const float*)d_in[4];
  const float* Wk   = (const float*)d_in[5];
  const float* bk   = (const float*)d_in[6];
  const float* Wv   = (const float*)d_in[7];
  const float* bv   = (const float*)d_in[8];
  const float* Wo   = (const float*)d_in[9];
  const float* bo   = (const float*)d_in[10];
  const float* rw   = (const float*)d_in[11];

  const size_t NEL = (size_t)4096 * 1024;   // 4M
  const size_t WEL = (size_t)1024 * 1024;   // 1M
  u16* hsb = (u16*)d_ws;                    // f16 hs [4096,1024]
  u16* wqb = hsb + NEL;                     // Wq,Wk,Wv contiguous; then Wo
  u16* wob = wqb + 3*WEL;
  u16* qhb = wob + WEL;                     // q,k head layout; v -> V^T [bh][d][s]
  u16* khb = qhb + NEL;
  u16* vtb = khb + NEL;
  u16* aob = hsb;                           // reuse: hs consumed by QKV GEMM

  cast_all<<<4096, 256, 0, stream>>>(hs, Wq, Wk, Wv, Wo, hsb);
  gemm_qkv<<<768, 256, 0, stream>>>(hsb, wqb, bq, bk, bv, qhb, khb, vtb, 4096, 1024);
  rmsrope<<<4096, 256, 0, stream>>>(qhb, khb, cosb, sinb, rw);
  attn<<<256, 512, 0, stream>>>(qhb, khb, vtb, aob);
  gemm_o<<<512, 256, 0, stream>>>(aob, wob, bo, (float*)d_out, 4096, 1024, 1024);
}

// Round 27
// 209.460 us; speedup vs baseline: 1.0298x; 1.0218x over previous
//
#include <hip/hip_runtime.h>

typedef unsigned short u16;
typedef __attribute__((ext_vector_type(8))) _Float16 half8;
typedef __attribute__((ext_vector_type(2))) __fp16 fp16x2;
typedef __attribute__((ext_vector_type(4))) float f32x4;
typedef __attribute__((ext_vector_type(16))) float f32x16;

#define MFMAH(A,B,C) __builtin_amdgcn_mfma_f32_16x16x32_f16(A,B,C,0,0,0)
#define MFMA32(A,B,C) __builtin_amdgcn_mfma_f32_32x32x16_f16(A,B,C,0,0,0)
#define LOG2E 1.4426950408889634f
#define C1 0.18033688011112042f   // 0.125 * log2(e)

__device__ __forceinline__ u16 f2h(float f){
  _Float16 h = (_Float16)f; u16 r; __builtin_memcpy(&r,&h,2); return r;
}
__device__ __forceinline__ float h2f(u16 v){
  _Float16 h; __builtin_memcpy(&h,&v,2); return (float)h;
}
__device__ __forceinline__ unsigned int pack_h2(float a, float b){
  fp16x2 h = __builtin_amdgcn_cvt_pkrtz(a,b);
  unsigned int r; __builtin_memcpy(&r,&h,4); return r;
}

// async global->LDS, 16B per lane; LDS dest = wave-uniform base + lane*16.
__device__ __forceinline__ void async_ld16(const void* g, void* l) {
  __builtin_amdgcn_global_load_lds(
      (const __attribute__((address_space(1))) unsigned int*)g,
      (__attribute__((address_space(3))) unsigned int*)l, 16, 0, 0);
}

// Cast hs (4M el) + Wq,Wk,Wv,Wo (1M each) fp32->f16 into contiguous ws.
__global__ __launch_bounds__(256) void cast_all(const float* __restrict__ hs,
    const float* __restrict__ wq, const float* __restrict__ wk,
    const float* __restrict__ wv, const float* __restrict__ wo,
    u16* __restrict__ dst)
{
  unsigned int i = blockIdx.x*256 + threadIdx.x;     // chunk of 8 elements
  size_t el = (size_t)i * 8;
  const float* src; size_t off;
  if (el < 4194304) { src = hs; off = el; }
  else {
    unsigned int r = (unsigned int)((el - 4194304) >> 20);
    src = (r==0)?wq:(r==1)?wk:(r==2)?wv:wo;
    off = (el - 4194304) & 1048575;
  }
  float4 a = *reinterpret_cast<const float4*>(src+off);
  float4 b = *reinterpret_cast<const float4*>(src+off+4);
  uint4 o = {pack_h2(a.x,a.y), pack_h2(a.z,a.w), pack_h2(b.x,b.y), pack_h2(b.z,b.w)};
  *reinterpret_cast<uint4*>(dst + el) = o;
}

// Fused QKV GEMM, 128x128 tiles, BK=32, 768 blocks (3/CU). W=[Wq;Wk;Wv].
// Best-measured BK=32 form (R11's BK=64+swizzle was null-to-negative:
// 2-phase critical path is stage+vmcnt+barrier).
// XCD-swizzled grid (T1): each XCD gets a 12n x 8m chunk so its W-panel (3MB)
// + A-panel (2MB) working set mostly fits the 4MB per-XCD L2.
// which = n0>>10: 0/1 -> q/k (SWAPPED operands, d-contiguous packed stores into
// [bh][s][d]); 2 -> v (normal order, s-contiguous packed stores into V^T [bh][d][s]).
__global__ __launch_bounds__(256) void gemm_qkv(const u16* __restrict__ A,
                                                const u16* __restrict__ W,
                                                const float* __restrict__ bqp,
                                                const float* __restrict__ bkp,
                                                const float* __restrict__ bvp,
                                                u16* __restrict__ qout,
                                                u16* __restrict__ kout,
                                                u16* __restrict__ vout,
                                                int M, int K)
{
  __shared__ __align__(16) u16 lds_a[128*32];
  __shared__ __align__(16) u16 lds_w[128*32];
  const int t = threadIdx.x;
  const int lane = t & 63, wave = t >> 6;
  const int wm = wave >> 1, wn = wave & 1;
  const int lr = lane & 15, quad = lane >> 4;
  // XCD-bijective decode: flat 0..767, xcd = flat&7 (HW round-robin),
  // per-XCD chunk = 12 n-blocks x 8 m-blocks.
  const int flat = blockIdx.x;
  const int xcd = flat & 7, slot = flat >> 3;     // slot 0..95
  const int ln = slot % 12, lm = slot / 12;       // 0..11, 0..7
  const int n0 = ((xcd & 1) * 12 + ln) * 128;
  const int m0 = ((xcd >> 1) * 8 + lm) * 128;
  const int wbase = t & 192;
  const int which = n0 >> 10;

  const f32x4 fzero = {0.f,0.f,0.f,0.f};
  f32x4 acc[4][4];
  #pragma unroll
  for (int i=0;i<4;++i)
    #pragma unroll
    for (int j=0;j<4;++j) acc[i][j] = fzero;

  if (which < 2) {                 // ---- q/k: swapped operands, D[n][m] ----
    for (int k0 = 0; k0 < K; k0 += 32) {
      __syncthreads();
      #pragma unroll
      for (int it=0; it<2; ++it) {
        int idx = it*256 + t;
        int row = idx >> 2, c8 = (idx & 3) * 8;
        int lbase = (it*256 + wbase) * 8;
        async_ld16(&A[(size_t)(m0+row)*K + k0 + c8], &lds_a[lbase]);
        async_ld16(&W[(size_t)(n0+row)*K + k0 + c8], &lds_w[lbase]);
      }
      __syncthreads();
      half8 af[4], bfr[4];
      #pragma unroll
      for (int mt=0; mt<4; ++mt)
        af[mt] = *reinterpret_cast<const half8*>(&lds_a[(wm*64 + mt*16 + lr)*32 + quad*8]);
      #pragma unroll
      for (int nt=0; nt<4; ++nt)
        bfr[nt] = *reinterpret_cast<const half8*>(&lds_w[(wn*64 + nt*16 + lr)*32 + quad*8]);
      #pragma unroll
      for (int mt=0; mt<4; ++mt)
        #pragma unroll
        for (int nt=0; nt<4; ++nt)
          acc[mt][nt] = MFMAH(bfr[nt], af[mt], acc[mt][nt]);
    }
    const float* bp = which ? bkp : bqp;
    u16* dst = which ? kout : qout;
    #pragma unroll
    for (int nt=0; nt<4; ++nt) {
      int nn = (n0 & 1023) + wn*64 + nt*16 + quad*4;   // 4 consecutive n on regs
      float4 bv = *reinterpret_cast<const float4*>(&bp[nn]);
      int hh = nn >> 6, d4 = nn & 63;
      #pragma unroll
      for (int mt=0; mt<4; ++mt) {
        int m = m0 + wm*64 + mt*16 + lr;
        int b = m >> 11, s = m & 2047;
        uint2 o = {pack_h2(acc[mt][nt][0]+bv.x, acc[mt][nt][1]+bv.y),
                   pack_h2(acc[mt][nt][2]+bv.z, acc[mt][nt][3]+bv.w)};
        *reinterpret_cast<uint2*>(&dst[((size_t)(b*16 + hh)*2048 + s)*64 + d4]) = o;
      }
    }
  } else {                         // ---- v: normal order, D[m][n] -> V^T ----
    for (int k0 = 0; k0 < K; k0 += 32) {
      __syncthreads();
      #pragma unroll
      for (int it=0; it<2; ++it) {
        int idx = it*256 + t;
        int row = idx >> 2, c8 = (idx & 3) * 8;
        int lbase = (it*256 + wbase) * 8;
        async_ld16(&A[(size_t)(m0+row)*K + k0 + c8], &lds_a[lbase]);
        async_ld16(&W[(size_t)(n0+row)*K + k0 + c8], &lds_w[lbase]);
      }
      __syncthreads();
      half8 af[4], bfr[4];
      #pragma unroll
      for (int mt=0; mt<4; ++mt)
        af[mt] = *reinterpret_cast<const half8*>(&lds_a[(wm*64 + mt*16 + lr)*32 + quad*8]);
      #pragma unroll
      for (int nt=0; nt<4; ++nt)
        bfr[nt] = *reinterpret_cast<const half8*>(&lds_w[(wn*64 + nt*16 + lr)*32 + quad*8]);
      #pragma unroll
      for (int mt=0; mt<4; ++mt)
        #pragma unroll
        for (int nt=0; nt<4; ++nt)
          acc[mt][nt] = MFMAH(af[mt], bfr[nt], acc[mt][nt]);
    }
    #pragma unroll
    for (int nt=0; nt<4; ++nt) {
      int nn = (n0 & 1023) + wn*64 + nt*16 + lr;
      float bv = bvp[nn];
      int hh = nn >> 6, d = nn & 63;
      #pragma unroll
      for (int mt=0; mt<4; ++mt) {
        int m = m0 + wm*64 + mt*16 + quad*4;
        int b = m >> 11, s = m & 2047;
        uint2 o = {pack_h2(acc[mt][nt][0]+bv, acc[mt][nt][1]+bv),
                   pack_h2(acc[mt][nt][2]+bv, acc[mt][nt][3]+bv)};
        *reinterpret_cast<uint2*>(&vout[((size_t)(b*16 + hh)*64 + d)*2048 + s]) = o;
      }
    }
  }
}

// Out-proj GEMM, SWAPPED operands: lane holds 4 consecutive n -> float4 stores.
// XCD-swizzled grid (T1): each XCD gets 16n x 4m (W 2MB + A 1MB fits L2).
__global__ __launch_bounds__(256) void gemm_o(const u16* __restrict__ A,
                                              const u16* __restrict__ W,
                                              const float* __restrict__ bias,
                                              float* __restrict__ O,
                                              int M, int N, int K)
{
  __shared__ __align__(16) u16 lds_a[128*32];
  __shared__ __align__(16) u16 lds_w[64*32];
  const int t = threadIdx.x;
  const int lane = t & 63, wm = t >> 6;      // wave owns 32 M-rows
  const int lr = lane & 15, quad = lane >> 4;
  const int flat = blockIdx.x;
  const int xcd = flat & 7, slot = flat >> 3;     // slot 0..63
  const int n0 = (slot & 15) * 64;
  const int m0 = ((xcd << 2) + (slot >> 4)) * 128;
  const int wbase = t & 192;

  const f32x4 fzero = {0.f,0.f,0.f,0.f};
  f32x4 acc[2][4];
  #pragma unroll
  for (int i=0;i<2;++i)
    #pragma unroll
    for (int j=0;j<4;++j) acc[i][j] = fzero;

  for (int k0 = 0; k0 < K; k0 += 32) {
    __syncthreads();
    #pragma unroll
    for (int it=0; it<2; ++it) {
      int idx = it*256 + t;
      int row = idx >> 2, c8 = (idx & 3) * 8;
      int lbase = (it*256 + wbase) * 8;
      async_ld16(&A[(size_t)(m0+row)*K + k0 + c8], &lds_a[lbase]);
    }
    async_ld16(&W[(size_t)(n0 + (t>>2))*K + k0 + (t&3)*8], &lds_w[wbase*8]);
    __syncthreads();
    half8 af[2], bfr[4];
    #pragma unroll
    for (int mt=0; mt<2; ++mt)
      af[mt] = *reinterpret_cast<const half8*>(&lds_a[(wm*32 + mt*16 + lr)*32 + quad*8]);
    #pragma unroll
    for (int nt=0; nt<4; ++nt)
      bfr[nt] = *reinterpret_cast<const half8*>(&lds_w[(nt*16 + lr)*32 + quad*8]);
    #pragma unroll
    for (int mt=0; mt<2; ++mt)
      #pragma unroll
      for (int nt=0; nt<4; ++nt)
        acc[mt][nt] = MFMAH(bfr[nt], af[mt], acc[mt][nt]);   // D[n][m]
  }

  #pragma unroll
  for (int nt=0; nt<4; ++nt) {
    int nb = n0 + nt*16 + quad*4;
    float4 bv = *reinterpret_cast<const float4*>(&bias[nb]);
    #pragma unroll
    for (int mt=0; mt<2; ++mt) {
      int m = m0 + wm*32 + mt*16 + lr;
      float4 o = {acc[mt][nt][0]+bv.x, acc[mt][nt][1]+bv.y,
                  acc[mt][nt][2]+bv.z, acc[mt][nt][3]+bv.w};
      *reinterpret_cast<float4*>(&O[(size_t)m * N + nb]) = o;
    }
  }
}

// In-place RMSNorm (over 1024 pre-split channels) + RoPE on [B,H,S,D] f16.
// One 256-thread block handles BOTH q and k for one (b,s): waves 0-1 = q,
// waves 2-3 = k. Reductions per-half via red[4].
__global__ __launch_bounds__(256) void rmsrope(u16* __restrict__ qb, u16* __restrict__ kb,
                                               const float* __restrict__ cosb,
                                               const float* __restrict__ sinb,
                                               const float* __restrict__ w)
{
  const int bs = blockIdx.x;
  const int b = bs >> 11, s = bs & 2047;
  const int t = threadIdx.x;                 // 256
  u16* buf = (t & 128) ? kb : qb;
  const int tl = t & 127;
  const int h = tl >> 3, d0 = (tl & 7) * 4;
  size_t base = ((size_t)(b*16+h)*2048 + s)*64;

  uint2 u1 = *reinterpret_cast<const uint2*>(&buf[base + d0]);
  uint2 u2 = *reinterpret_cast<const uint2*>(&buf[base + d0 + 32]);
  u16 a1[4], a2[4];
  __builtin_memcpy(a1, &u1, 8); __builtin_memcpy(a2, &u2, 8);
  float x1[4], x2[4];
  float ss = 0.f;
  #pragma unroll
  for (int j=0;j<4;++j){
    x1[j] = h2f(a1[j]); x2[j] = h2f(a2[j]);
    ss += x1[j]*x1[j] + x2[j]*x2[j];
  }
  #pragma unroll
  for (int off=32; off>0; off>>=1) ss += __shfl_xor(ss, off, 64);
  __shared__ float red[4];
  if ((t & 63) == 0) red[t>>6] = ss;
  __syncthreads();
  float tot = (t & 128) ? (red[2] + red[3]) : (red[0] + red[1]);
  float r = rsqrtf(tot * (1.0f/1024.0f) + 1e-6f);

  float4 w1 = *reinterpret_cast<const float4*>(&w[h*64+d0]);
  float4 w2 = *reinterpret_cast<const float4*>(&w[h*64+d0+32]);
  float4 c1 = *reinterpret_cast<const float4*>(&cosb[s*64+d0]);
  float4 s1 = *reinterpret_cast<const float4*>(&sinb[s*64+d0]);
  float4 c2 = *reinterpret_cast<const float4*>(&cosb[s*64+d0+32]);
  float4 s2 = *reinterpret_cast<const float4*>(&sinb[s*64+d0+32]);
  float n1[4] = {x1[0]*r*w1.x, x1[1]*r*w1.y, x1[2]*r*w1.z, x1[3]*r*w1.w};
  float n2[4] = {x2[0]*r*w2.x, x2[1]*r*w2.y, x2[2]*r*w2.z, x2[3]*r*w2.w};
  float o1[4] = {n1[0]*c1.x - n2[0]*s1.x, n1[1]*c1.y - n2[1]*s1.y,
                 n1[2]*c1.z - n2[2]*s1.z, n1[3]*c1.w - n2[3]*s1.w};
  float o2[4] = {n2[0]*c2.x + n1[0]*s2.x, n2[1]*c2.y + n1[1]*s2.y,
                 n2[2]*c2.z + n1[2]*s2.z, n2[3]*c2.w + n1[3]*s2.w};
  uint2 v1 = {pack_h2(o1[0],o1[1]), pack_h2(o1[2],o1[3])};
  uint2 v2 = {pack_h2(o2[0],o2[1]), pack_h2(o2[2],o2[3])};
  *reinterpret_cast<uint2*>(&buf[base + d0])      = v1;
  *reinterpret_cast<uint2*>(&buf[base + d0 + 32]) = v2;
}

// Flash attention, 32x32x16 MFMA. FINAL configuration (best measured:
// 210.5us total; attn 50.2-56.1us across 15 runs, VGPR 116, 0 conflicts).
// Structure: 64 q-rows/wave (qh=0,1 sub-tiles), BLOCK_Q=256, 8 waves =
// 4 q-waves x 2 key-groups (tiles 0-15/16-31), grid 256 = 1 block/CU.
// K/V fragments read from LDS ONCE, reused for both q-halves; QK and PV
// are 2 independent MFMA chains each. lsum on VALU (4 partials + shfl_xor).
// T14: prefetch issued after barrier, LDS-write after compute.
// S^T = K.Q^T (A=K,B=Q); O^T = V^T.P^T with vbuf in bit-swapped virtual-key
// order so S^T C-layout regs feed PV B-frags with no shuffles.
// pad-72 rows: 0 bank conflicts + coalesced staging. T1: XCD-bijective grid,
// 4 heads/XCD -> K/V 2MB fits per-XCD L2 (FETCH 69.7->12.3MB verified).
// __launch_bounds__(512,1): 2nd arg = blocks/CU on this toolchain.
// Mask is ADDITIVE (+1 allowed / +0 disallowed): all 32 tiles contribute.
// PLATEAU (15 runs, 210.5-216.8us): latency-bound at ~6% true MFMA occupancy;
// register file caps waves/SIMD. Tested-null/negative: T5/ones-MFMA (R8/R10),
// BK=64+T2 (R11), T15 pipeline (R14), LDS-diet (R3/R4). Further gains
// require the full co-designed 8-phase / 4-cluster rewrite (T2+T3+T4+T5).
__global__ __launch_bounds__(512, 1) void attn(const u16* __restrict__ qh,
                                               const u16* __restrict__ kh,
                                               const u16* __restrict__ vt,
                                               u16* __restrict__ ao)
{
  __shared__ __align__(16) u16 kbuf[2][2][64*72];   // [group][dbuf][key][d], pad 72
  __shared__ __align__(16) u16 vbuf[2][2][64*72];   // [group][dbuf][d][virtual-k]
  const int t = threadIdx.x;
  const int lane = t & 63, w = t >> 6;           // 8 waves
  const int g = w >> 2, wq = w & 3;              // key-group, q-wave
  const int ql = lane & 31, hf = lane >> 5;
  // XCD-bijective decode (flat 0..255, HW round-robins xcd = flat&7)
  const int flat = blockIdx.x;
  const int xcd = flat & 7, slot = flat >> 3;    // slot 0..31
  const int bh = xcd + ((slot >> 3) << 3);       // {xcd, xcd+8, xcd+16, xcd+24}
  const int qbase = (slot & 7) * 256;
  const int b = bh >> 4, h = bh & 15;
  const size_t hb = (size_t)bh * 2048 * 64;
  const u16* qp = qh + hb;
  const u16* kp = kh + hb;
  const u16* vtp = vt + hb;

  // Q fragments for both 32-q halves of this wave's 64 q rows.
  half8 qf[2][4];                                // [qh][s]: Q[d=s*16+hf*8+j][q]
  #pragma unroll
  for (int qh2=0; qh2<2; ++qh2) {
    int qa = qbase + wq*64 + qh2*32 + ql;
    #pragma unroll
    for (int s=0;s<4;++s)
      qf[qh2][s] = *reinterpret_cast<const half8*>(&qp[(size_t)qa*64 + s*16 + hf*8]);
  }

  // staging: 256 threads per group stage that group's tile.
  const int lt = t & 255;
  const int row = lt >> 3;                       // 0..31
  const int cc = lt & 7;
  const int base2 = 32*(cc>>2) + 16*((cc>>1)&1) + 4*(cc&1);  // keys base2+{0..3,8..11}
  const int kofs = row*72 + cc*8;
  const u16* kg = kp + (size_t)(g*1024 + row)*64 + cc*8;
  const u16* vg = vtp + (size_t)row*2048 + g*1024 + base2;

  const f32x16 fz16 = {0.f,0.f,0.f,0.f,0.f,0.f,0.f,0.f,0.f,0.f,0.f,0.f,0.f,0.f,0.f,0.f};
  f32x16 oacc[2][2];                             // [qh][dh]
  oacc[0][0]=fz16; oacc[0][1]=fz16; oacc[1][0]=fz16; oacc[1][1]=fz16;
  float lsum[2] = {0.f, 0.f};
  const int diag = (qbase + wq*64) >> 6;         // same tile for both qh halves

  // stage tile 0 of this group's range into buffer 0
  {
    uint4 k0v = *reinterpret_cast<const uint4*>(kg);
    uint4 k1v = *reinterpret_cast<const uint4*>(kg + 32*64);
    uint2 a0 = *reinterpret_cast<const uint2*>(vg);
    uint2 a1 = *reinterpret_cast<const uint2*>(vg + 8);
    uint2 b0 = *reinterpret_cast<const uint2*>(vg + (size_t)32*2048);
    uint2 b1 = *reinterpret_cast<const uint2*>(vg + (size_t)32*2048 + 8);
    *reinterpret_cast<uint4*>(&kbuf[g][0][kofs])        = k0v;
    *reinterpret_cast<uint4*>(&kbuf[g][0][kofs+32*72])  = k1v;
    uint4 v0 = {a0.x,a0.y,a1.x,a1.y};
    uint4 v1 = {b0.x,b0.y,b1.x,b1.y};
    *reinterpret_cast<uint4*>(&vbuf[g][0][kofs])        = v0;
    *reinterpret_cast<uint4*>(&vbuf[g][0][kofs+32*72])  = v1;
  }

  for (int kt=0; kt<16; ++kt) {
    __syncthreads();                             // buffers for kt ready
    // T14: issue next-tile loads after the barrier; compute covers latency.
    uint4 k0n, k1n; uint2 a0n, a1n, b0n, b1n;
    if (kt < 15) {
      const u16* kgn = kg + (size_t)(kt+1)*4096;
      const u16* vgn = vg + (kt+1)*64;
      k0n = *reinterpret_cast<const uint4*>(kgn);
      k1n = *reinterpret_cast<const uint4*>(kgn + 32*64);
      a0n = *reinterpret_cast<const uint2*>(vgn);
      a1n = *reinterpret_cast<const uint2*>(vgn + 8);
      b0n = *reinterpret_cast<const uint2*>(vgn + (size_t)32*2048);
      b1n = *reinterpret_cast<const uint2*>(vgn + (size_t)32*2048 + 8);
    }
    const u16* kb = &kbuf[g][kt & 1][0];
    const u16* vb = &vbuf[g][kt & 1][0];
    const int gkt = (g << 4) + kt;               // global key-tile index

    // S^T = K.Q^T (two 32-key halves x two q-halves); K-frags read ONCE.
    unsigned int pk[2][4][4];                    // [qh][st][word]
    #pragma unroll
    for (int kh2=0; kh2<2; ++kh2) {
      half8 kf[4];
      #pragma unroll
      for (int s=0;s<4;++s)
        __builtin_memcpy(&kf[s], &kb[(kh2*32+ql)*72 + s*16 + hf*8], 16);
      f32x16 z0 = fz16, z1 = fz16;               // independent chains (2x ILP)
      #pragma unroll
      for (int s=0;s<4;++s) z0 = MFMA32(kf[s], qf[0][s], z0);
      #pragma unroll
      for (int s=0;s<4;++s) z1 = MFMA32(kf[s], qf[1][s], z1);

      #pragma unroll
      for (int qh2=0; qh2<2; ++qh2) {
        const f32x16& z = qh2 ? z1 : z0;
        const int qa = qbase + wq*64 + qh2*32 + ql;
        float p[16];
        if (gkt != diag) {
          float ml = (gkt < diag) ? LOG2E : 0.0f;
          #pragma unroll
          for (int r=0;r<16;++r)
            p[r] = __builtin_amdgcn_exp2f(__builtin_fmaf(z[r], C1, ml));
        } else {
          #pragma unroll
          for (int r=0;r<16;++r) {
            int key = gkt*64 + kh2*32 + (r&3) + 8*(r>>2) + 4*hf;
            float ml = (key <= qa) ? LOG2E : 0.0f;
            p[r] = __builtin_amdgcn_exp2f(__builtin_fmaf(z[r], C1, ml));
          }
        }
        float ls0=0.f, ls1=0.f, ls2=0.f, ls3=0.f;  // 4-partial lsum (ILP)
        #pragma unroll
        for (int r=0;r<16;r+=4){ ls0+=p[r]; ls1+=p[r+1]; ls2+=p[r+2]; ls3+=p[r+3]; }
        lsum[qh2] += (ls0+ls1)+(ls2+ls3);
        #pragma unroll
        for (int t2=0;t2<2;++t2)
          #pragma unroll
          for (int jj=0;jj<4;++jj)
            pk[qh2][kh2*2+t2][jj] = pack_h2(p[t2*8+jj*2], p[t2*8+jj*2+1]);
      }
    }

    // O^T += V^T . P^T; V-frags read ONCE, reused for both q-halves.
    #pragma unroll
    for (int st=0;st<4;++st) {
      half8 vf0, vf1;
      __builtin_memcpy(&vf0, &vb[(0*32+ql)*72 + st*16 + hf*8], 16);
      __builtin_memcpy(&vf1, &vb[(1*32+ql)*72 + st*16 + hf*8], 16);
      #pragma unroll
      for (int qh2=0; qh2<2; ++qh2) {
        uint4 pq = {pk[qh2][st][0], pk[qh2][st][1], pk[qh2][st][2], pk[qh2][st][3]};
        half8 pf; __builtin_memcpy(&pf, &pq, 16);
        oacc[qh2][0] = MFMA32(vf0, pf, oacc[qh2][0]);
        oacc[qh2][1] = MFMA32(vf1, pf, oacc[qh2][1]);
      }
    }

    // write prefetched tile (vmcnt wait lands here, covered by compute)
    if (kt < 15) {
      u16* kwn = &kbuf[g][(kt+1)&1][kofs];
      u16* vwn = &vbuf[g][(kt+1)&1][kofs];
      *reinterpret_cast<uint4*>(kwn)         = k0n;
      *reinterpret_cast<uint4*>(kwn + 32*72) = k1n;
      uint4 v0 = {a0n.x,a0n.y,a1n.x,a1n.y};
      uint4 v1 = {b0n.x,b0n.y,b1n.x,b1n.y};
      *reinterpret_cast<uint4*>(vwn)         = v0;
      *reinterpret_cast<uint4*>(vwn + 32*72) = v1;
    }
  }

  // combine kh halves of lsum (lanes hf=0/1 hold disjoint key subsets)
  lsum[0] += __shfl_xor(lsum[0], 32, 64);
  lsum[1] += __shfl_xor(lsum[1], 32, 64);

  // ---- combine the two key-groups through LDS ----
  // qh=0 O-partials in kbuf (8 slices x 256 x 16B = 32KB), qh=1 in vbuf
  // (32KB); lsum in vbuf tail (+32KB, 2x256 floats).
  __syncthreads();                               // all compute on kbuf/vbuf done
  f32x4* xch0 = (f32x4*)&kbuf[0][0][0];
  f32x4* xch1 = (f32x4*)&vbuf[0][0][0];
  float* xls  = (float*)((char*)&vbuf[0][0][0] + 32768);
  const int idx = wq*64 + lane;
  if (g == 1) {
    #pragma unroll
    for (int qh2=0; qh2<2; ++qh2) {
      f32x4* xch = qh2 ? xch1 : xch0;
      #pragma unroll
      for (int dh=0; dh<2; ++dh)
        #pragma unroll
        for (int rq=0; rq<4; ++rq) {
          f32x4 v = {oacc[qh2][dh][rq*4+0], oacc[qh2][dh][rq*4+1],
                     oacc[qh2][dh][rq*4+2], oacc[qh2][dh][rq*4+3]};
          xch[(dh*4+rq)*256 + idx] = v;
        }
      xls[qh2*256 + idx] = lsum[qh2];
    }
  }
  __syncthreads();
  if (g == 0) {
    #pragma unroll
    for (int qh2=0; qh2<2; ++qh2) {
      f32x4* xch = qh2 ? xch1 : xch0;
      float inv = 1.0f / (lsum[qh2] + xls[qh2*256 + idx]);
      int qa = qbase + wq*64 + qh2*32 + ql;
      size_t rowbase = ((size_t)(b*2048 + qa))*1024 + h*64;
      #pragma unroll
      for (int dh=0; dh<2; ++dh)
        #pragma unroll
        for (int rq=0; rq<4; ++rq) {
          int dd = dh*32 + 8*rq + 4*hf;
          f32x4 v = xch[(dh*4+rq)*256 + idx];
          uint2 o = {pack_h2((oacc[qh2][dh][rq*4+0]+v.x)*inv, (oacc[qh2][dh][rq*4+1]+v.y)*inv),
                     pack_h2((oacc[qh2][dh][rq*4+2]+v.z)*inv, (oacc[qh2][dh][rq*4+3]+v.w)*inv)};
          *reinterpret_cast<uint2*>(&ao[rowbase + dd]) = o;
        }
    }
  }
}

extern "C" void kernel_launch(void* const* d_in, const int* in_sizes, int n_in,
                              void* d_out, int out_size, void* d_ws, size_t ws_size,
                              hipStream_t stream)
{
  const float* hs   = (const float*)d_in[0];
  const float* cosb = (const float*)d_in[1];
  const float* sinb = (const float*)d_in[2];
  const float* Wq   = (const float*)d_in[3];
  const float* bq   = (const float*)d_in[4];
  const float* Wk   = (const float*)d_in[5];
  const float* bk   = (const float*)d_in[6];
  const float* Wv   = (const float*)d_in[7];
  const float* bv   = (const float*)d_in[8];
  const float* Wo   = (const float*)d_in[9];
  const float* bo   = (const float*)d_in[10];
  const float* rw   = (const float*)d_in[11];

  const size_t NEL = (size_t)4096 * 1024;   // 4M
  const size_t WEL = (size_t)1024 * 1024;   // 1M
  u16* hsb = (u16*)d_ws;                    // f16 hs [4096,1024]
  u16* wqb = hsb + NEL;                     // Wq,Wk,Wv contiguous; then Wo
  u16* wob = wqb + 3*WEL;
  u16* qhb = wob + WEL;                     // q,k head layout; v -> V^T [bh][d][s]
  u16* khb = qhb + NEL;
  u16* vtb = khb + NEL;
  u16* aob = hsb;                           // reuse: hs consumed by QKV GEMM

  cast_all<<<4096, 256, 0, stream>>>(hs, Wq, Wk, Wv, Wo, hsb);
  gemm_qkv<<<768, 256, 0, stream>>>(hsb, wqb, bq, bk, bv, qhb, khb, vtb, 4096, 1024);
  rmsrope<<<4096, 256, 0, stream>>>(qhb, khb, cosb, sinb, rw);
  attn<<<256, 512, 0, stream>>>(qhb, khb, vtb, aob);
  gemm_o<<<512, 256, 0, stream>>>(aob, wob, bo, (float*)d_out, 4096, 1024, 1024);
}